// Round 1
// baseline (1747.635 us; speedup 1.0000x reference)
//
#include <hip/hip_runtime.h>
#include <math.h>

// Problem constants
#define NL 4096     // L patches
#define NQ 4096     // HS*WS pixels
#define NC 64       // channels
#define NCK 1024    // C*KP*KP = 64*16
#define SCALE 10.0f

// ---------------------------------------------------------------------------
// K1: first diagonal fuse pass on the flattened [4096 x 4096] image.
// A1[r][c] = S[r-1][c-1] + S[r][c] + S[r+1][c+1]  (zero pad)
// ---------------------------------------------------------------------------
__global__ void fuse1(const float* __restrict__ S, float* __restrict__ A1) {
    int c = blockIdx.x * 256 + threadIdx.x;   // 0..4095
    int r = blockIdx.y;                       // 0..4095
    float acc = S[r * 4096 + c];
    if (r > 0 && c > 0)        acc += S[(r - 1) * 4096 + (c - 1)];
    if (r < 4095 && c < 4095)  acc += S[(r + 1) * 4096 + (c + 1)];
    A1[r * 4096 + c] = acc;
}

// ---------------------------------------------------------------------------
// K2: second diagonal fuse pass through the (hb<->wb, hs<->ws) transposed view.
// fused[hb,wb,hs,ws] = sum_d A1_view[wb*64+hb+d, ws*64+hs+d]  (zero pad),
// where A1_view[r2,c2] = A1[(r2&63)*64 + (r2>>6)][(c2&63)*64 + (c2>>6)].
// Output written in the original [l][q] layout.
// ---------------------------------------------------------------------------
__global__ void fuse2(const float* __restrict__ A1, float* __restrict__ F) {
    int l = blockIdx.x;               // 0..4095
    int hb = l >> 6, wb = l & 63;
    int r2 = wb * 64 + hb;
    for (int q = threadIdx.x; q < NQ; q += 256) {
        int hs = q >> 6, ws = q & 63;
        int c2 = ws * 64 + hs;
        float acc = 0.f;
        #pragma unroll
        for (int d = -1; d <= 1; ++d) {
            int r2d = r2 + d, c2d = c2 + d;
            if (r2d >= 0 && r2d < 4096 && c2d >= 0 && c2d < 4096) {
                int wbp = r2d >> 6, hbp = r2d & 63;
                int wsp = c2d >> 6, hsp = c2d & 63;
                acc += A1[(hbp * 64 + wbp) * 4096 + (hsp * 64 + wsp)];
            }
        }
        F[l * 4096 + q] = acc;
    }
}

// ---------------------------------------------------------------------------
// K3: masked softmax over l (rows) for each pixel q (column), in place.
// s(l,q) = F[l][q]*mm[l]*SCALE ; P[l][q] = mm[l]*exp(s-m_q)/sum_l exp(s-m_q)
// Block handles 64 consecutive q; 4 thread-groups stride over l. 3 passes
// (data is L3-resident between passes).
// ---------------------------------------------------------------------------
__global__ void softmaxP(float* __restrict__ F, const float* __restrict__ mm) {
    int qo = threadIdx.x & 63;
    int lg = threadIdx.x >> 6;        // 0..3
    int q = blockIdx.x * 64 + qo;
    __shared__ float red[4][64];

    float m = -1e30f;
    for (int li = lg; li < NL; li += 4) {
        float s = F[li * 4096 + q] * mm[li] * SCALE;
        m = fmaxf(m, s);
    }
    red[lg][qo] = m;
    __syncthreads();
    m = fmaxf(fmaxf(red[0][qo], red[1][qo]), fmaxf(red[2][qo], red[3][qo]));
    __syncthreads();

    float sum = 0.f;
    for (int li = lg; li < NL; li += 4) {
        float s = F[li * 4096 + q] * mm[li] * SCALE;
        sum += __expf(s - m);
    }
    red[lg][qo] = sum;
    __syncthreads();
    sum = red[0][qo] + red[1][qo] + red[2][qo] + red[3][qo];
    float inv = 1.0f / sum;

    for (int li = lg; li < NL; li += 4) {
        float v = F[li * 4096 + q];
        float s = v * mm[li] * SCALE;
        F[li * 4096 + q] = mm[li] * __expf(s - m) * inv;
    }
}

// ---------------------------------------------------------------------------
// K4: fp32 GEMM  Mo[M=4096 q][N=1024 ck] = sum_k P[k][m] * Wb[k][n]
// A (=P) is stored K-major [K][M]; B (=raw_w) is [K][N]. Classic tiled GEMM:
// 64x64 tile, BK=16, 256 threads, 4x4 accumulator per thread, padded LDS.
// ---------------------------------------------------------------------------
#define BM 64
#define BN 64
#define BK 16
__global__ __launch_bounds__(256) void gemmP(const float* __restrict__ A,
                                             const float* __restrict__ B,
                                             float* __restrict__ Cm) {
    __shared__ float As[BK][BM + 4];
    __shared__ float Bs[BK][BN + 4];
    int m0 = blockIdx.x * BM;
    int n0 = blockIdx.y * BN;
    int tx = threadIdx.x & 15;        // -> m sub-tile
    int ty = threadIdx.x >> 4;        // -> n sub-tile
    int lr = threadIdx.x >> 4;        // load row 0..15
    int lc = (threadIdx.x & 15) * 4;  // load col 0..60

    float acc[4][4] = {};
    for (int k0 = 0; k0 < NL; k0 += BK) {
        *(float4*)&As[lr][lc] = *(const float4*)&A[(k0 + lr) * 4096 + m0 + lc];
        *(float4*)&Bs[lr][lc] = *(const float4*)&B[(k0 + lr) * 1024 + n0 + lc];
        __syncthreads();
        #pragma unroll
        for (int kk = 0; kk < BK; ++kk) {
            float a[4], b[4];
            *(float4*)a = *(float4*)&As[kk][tx * 4];
            *(float4*)b = *(float4*)&Bs[kk][ty * 4];
            #pragma unroll
            for (int i = 0; i < 4; ++i)
                #pragma unroll
                for (int j = 0; j < 4; ++j)
                    acc[i][j] += a[i] * b[j];
        }
        __syncthreads();
    }
    #pragma unroll
    for (int i = 0; i < 4; ++i) {
        int mrow = m0 + tx * 4 + i;
        *(float4*)&Cm[mrow * 1024 + n0 + ty * 4] = *(float4*)acc[i];
    }
}

// ---------------------------------------------------------------------------
// K5: transposed-conv scatter (gather form). For each (c,oy,ox), sum the <=4
// contributing (iy,ky)x(ix,kx) combos from Mo[q][ck], divide by 4.
// ---------------------------------------------------------------------------
__global__ void scatterD(const float* __restrict__ Mo, float* __restrict__ Dc) {
    int idx = blockIdx.x * 256 + threadIdx.x;   // c*16384 + oy*128 + ox
    int ox = idx & 127, oy = (idx >> 7) & 127, c = idx >> 14;
    float acc = 0.f;
    #pragma unroll
    for (int ky = 0; ky < 4; ++ky) {
        int ty = oy + 1 - ky;
        if (ty & 1) continue;
        int iy = ty >> 1;
        if (iy < 0 || iy >= 64) continue;
        #pragma unroll
        for (int kx = 0; kx < 4; ++kx) {
            int txx = ox + 1 - kx;
            if (txx & 1) continue;
            int ix = txx >> 1;
            if (ix < 0 || ix >= 64) continue;
            acc += Mo[(iy * 64 + ix) * 1024 + c * 16 + ky * 4 + kx];
        }
    }
    Dc[idx] = acc * 0.25f;
}

// ---------------------------------------------------------------------------
// K6/K7: 3x3 conv (pad 1) + bias + ELU on [64][128][128].
// Block: one c_out x 2 rows x 128 cols; weights are block-uniform (scalar
// loads); input reads coalesced along x, L2-resident.
// ---------------------------------------------------------------------------
__global__ void conv3x3_elu(const float* __restrict__ X, const float* __restrict__ W,
                            const float* __restrict__ Bi, float* __restrict__ Y) {
    int co = blockIdx.x;
    int y = blockIdx.y * 2 + (threadIdx.x >> 7);
    int x = threadIdx.x & 127;
    int ky0 = (y == 0) ? 1 : 0, ky1 = (y == 127) ? 2 : 3;
    int kx0 = (x == 0) ? 1 : 0, kx1 = (x == 127) ? 2 : 3;
    float acc = Bi[co];
    const float* wp = W + co * 576;
    for (int ci = 0; ci < 64; ++ci) {
        const float* xp = X + ci * 16384;
        const float* wc = wp + ci * 9;
        for (int ky = ky0; ky < ky1; ++ky) {
            int yy = y + ky - 1;
            for (int kx = kx0; kx < kx1; ++kx) {
                int xx = x + kx - 1;
                acc += xp[yy * 128 + xx] * wc[ky * 3 + kx];
            }
        }
    }
    Y[co * 16384 + y * 128 + x] = acc > 0.f ? acc : expm1f(acc);
}

// ---------------------------------------------------------------------------
extern "C" void kernel_launch(void* const* d_in, const int* in_sizes, int n_in,
                              void* d_out, int out_size, void* d_ws, size_t ws_size,
                              hipStream_t stream) {
    const float* raw_w  = (const float*)d_in[0];  // [4096][1024]
    const float* mm     = (const float*)d_in[1];  // [4096]
    const float* scores = (const float*)d_in[2];  // [4096][4096]
    const float* w1     = (const float*)d_in[3];
    const float* b1     = (const float*)d_in[4];
    const float* w2     = (const float*)d_in[5];
    const float* b2     = (const float*)d_in[6];
    float* out = (float*)d_out;

    char* ws = (char*)d_ws;
    float* A1 = (float*)ws;                         // 64 MiB (dead after fuse2)
    float* F  = (float*)(ws + (64ull << 20));       // 64 MiB, becomes P in place
    float* Mo = (float*)ws;                         // 16 MiB (reuses A1 space)
    float* Dc = (float*)(ws + (16ull << 20));       // 4 MiB
    float* Y1 = (float*)(ws + (20ull << 20));       // 4 MiB

    fuse1<<<dim3(16, 4096), 256, 0, stream>>>(scores, A1);
    fuse2<<<4096, 256, 0, stream>>>(A1, F);
    softmaxP<<<64, 256, 0, stream>>>(F, mm);
    gemmP<<<dim3(64, 16), 256, 0, stream>>>(F, raw_w, Mo);
    scatterD<<<4096, 256, 0, stream>>>(Mo, Dc);
    conv3x3_elu<<<dim3(64, 64), 256, 0, stream>>>(Dc, w1, b1, Y1);
    conv3x3_elu<<<dim3(64, 64), 256, 0, stream>>>(Y1, w2, b2, out);
}

// Round 2
// 716.234 us; speedup vs baseline: 2.4400x; 2.4400x over previous
//
#include <hip/hip_runtime.h>
#include <hip/hip_bf16.h>
#include <math.h>

// Problem constants
#define NL 4096     // L patches
#define NQ 4096     // HS*WS pixels
#define SCALE 10.0f

typedef __bf16 bf16x8 __attribute__((ext_vector_type(8)));
typedef float  f32x4  __attribute__((ext_vector_type(4)));

#define GLOAD_LDS16(gp, lp)                                                        \
    __builtin_amdgcn_global_load_lds((const __attribute__((address_space(1))) void*)(gp), \
                                     (__attribute__((address_space(3))) void*)(lp), \
                                     16, 0, 0)

// ---------------------------------------------------------------------------
// K1: first diagonal fuse pass on the flattened [4096 x 4096] image.
// ---------------------------------------------------------------------------
__global__ void fuse1(const float* __restrict__ S, float* __restrict__ A1) {
    int c = blockIdx.x * 256 + threadIdx.x;
    int r = blockIdx.y;
    float acc = S[r * 4096 + c];
    if (r > 0 && c > 0)        acc += S[(r - 1) * 4096 + (c - 1)];
    if (r < 4095 && c < 4095)  acc += S[(r + 1) * 4096 + (c + 1)];
    A1[r * 4096 + c] = acc;
}

// ---------------------------------------------------------------------------
// K2: second diagonal fuse pass through the transposed view.
// ---------------------------------------------------------------------------
__global__ void fuse2(const float* __restrict__ A1, float* __restrict__ F) {
    int l = blockIdx.x;
    int hb = l >> 6, wb = l & 63;
    int r2 = wb * 64 + hb;
    for (int q = threadIdx.x; q < NQ; q += 256) {
        int hs = q >> 6, ws = q & 63;
        int c2 = ws * 64 + hs;
        float acc = 0.f;
        #pragma unroll
        for (int d = -1; d <= 1; ++d) {
            int r2d = r2 + d, c2d = c2 + d;
            if (r2d >= 0 && r2d < 4096 && c2d >= 0 && c2d < 4096) {
                int wbp = r2d >> 6, hbp = r2d & 63;
                int wsp = c2d >> 6, hsp = c2d & 63;
                acc += A1[(hbp * 64 + wbp) * 4096 + (hsp * 64 + wsp)];
            }
        }
        F[l * 4096 + q] = acc;
    }
}

// ---------------------------------------------------------------------------
// S1: partial softmax stats. Block (qt,lc): 64 q cols, 128-l chunk.
// Per-thread caches 32 s-values in registers; 4 l-groups reduced via LDS.
// ---------------------------------------------------------------------------
__global__ __launch_bounds__(256) void softPart(const float* __restrict__ F,
                                                const float* __restrict__ mm,
                                                float* __restrict__ Pm,
                                                float* __restrict__ Ps) {
    int qt = blockIdx.x, lc = blockIdx.y;
    int qo = threadIdx.x & 63, lg = threadIdx.x >> 6;
    int q = qt * 64 + qo;
    __shared__ float red[4][64];

    float sv[32];
    float m = -1e30f;
    #pragma unroll
    for (int i = 0; i < 32; ++i) {
        int l = lc * 128 + i * 4 + lg;
        float s = F[(size_t)l * 4096 + q] * mm[l] * SCALE;
        sv[i] = s;
        m = fmaxf(m, s);
    }
    red[lg][qo] = m;
    __syncthreads();
    m = fmaxf(fmaxf(red[0][qo], red[1][qo]), fmaxf(red[2][qo], red[3][qo]));
    __syncthreads();

    float sum = 0.f;
    #pragma unroll
    for (int i = 0; i < 32; ++i) sum += __expf(sv[i] - m);
    red[lg][qo] = sum;
    __syncthreads();
    if (lg == 0) {
        sum = red[0][qo] + red[1][qo] + red[2][qo] + red[3][qo];
        Pm[lc * 4096 + q] = m;
        Ps[lc * 4096 + q] = sum;
    }
}

// ---------------------------------------------------------------------------
// S2: combine 32 chunk partials per q.
// ---------------------------------------------------------------------------
__global__ void softComb(const float* __restrict__ Pm, const float* __restrict__ Ps,
                         float* __restrict__ Qm, float* __restrict__ Qi) {
    int q = blockIdx.x * 256 + threadIdx.x;
    float M = -1e30f;
    #pragma unroll
    for (int i = 0; i < 32; ++i) M = fmaxf(M, Pm[i * 4096 + q]);
    float S = 0.f;
    #pragma unroll
    for (int i = 0; i < 32; ++i) S += Ps[i * 4096 + q] * __expf(Pm[i * 4096 + q] - M);
    Qm[q] = M;
    Qi[q] = 1.0f / S;
}

// ---------------------------------------------------------------------------
// S3: normalize + bf16 convert + transpose. Pt[m=q][k=l] = bf16(P[l][q]).
// ---------------------------------------------------------------------------
__global__ __launch_bounds__(256) void normTransP(const float* __restrict__ F,
                                                  const float* __restrict__ mm,
                                                  const float* __restrict__ Qm,
                                                  const float* __restrict__ Qi,
                                                  __hip_bfloat16* __restrict__ Pt) {
    __shared__ float T[64][65];
    int qt = blockIdx.x, lt = blockIdx.y;
    int c = threadIdx.x & 63;
    int q = qt * 64 + c;
    float qm = Qm[q], qi = Qi[q];
    #pragma unroll
    for (int p = 0; p < 16; ++p) {
        int r = p * 4 + (threadIdx.x >> 6);
        int l = lt * 64 + r;
        float mml = mm[l];
        float s = F[(size_t)l * 4096 + q] * mml * SCALE - qm;
        T[r][c] = mml * __expf(s) * qi;
    }
    __syncthreads();
    #pragma unroll
    for (int p = 0; p < 16; ++p) {
        int r = p * 4 + (threadIdx.x >> 6);   // q-local (output row)
        Pt[(size_t)(qt * 64 + r) * 4096 + lt * 64 + c] = (__hip_bfloat16)T[c][r];
    }
}

// ---------------------------------------------------------------------------
// Wt: transpose + convert raw_w [k][n] fp32 -> Wt [n][k] bf16.
// ---------------------------------------------------------------------------
__global__ __launch_bounds__(256) void transW(const float* __restrict__ Wsrc,
                                              __hip_bfloat16* __restrict__ Wt) {
    __shared__ float T[64][65];
    int nt = blockIdx.x, kt = blockIdx.y;
    int c = threadIdx.x & 63;
    #pragma unroll
    for (int p = 0; p < 16; ++p) {
        int r = p * 4 + (threadIdx.x >> 6);
        T[r][c] = Wsrc[(size_t)(kt * 64 + r) * 1024 + nt * 64 + c];
    }
    __syncthreads();
    #pragma unroll
    for (int p = 0; p < 16; ++p) {
        int r = p * 4 + (threadIdx.x >> 6);   // n-local
        Wt[(size_t)(nt * 64 + r) * 4096 + kt * 64 + c] = (__hip_bfloat16)T[c][r];
    }
}

// ---------------------------------------------------------------------------
// K4: bf16 MFMA GEMM. Mo[m=4096][n=1024] = sum_k Pt[m][k] * Wt[n][k]^T.
// 128x128 tile, BK=32, 4 waves (2x2) each 64x64 = 4x4 16x16x32 fragments.
// Double-buffered LDS via global_load_lds (width 16).
// ---------------------------------------------------------------------------
__global__ __launch_bounds__(256) void gemmMfma(const __hip_bfloat16* __restrict__ Ab,
                                                const __hip_bfloat16* __restrict__ Bb,
                                                float* __restrict__ Cm) {
    __shared__ __align__(16) __hip_bfloat16 As[2][128][32];  // 16 KiB
    __shared__ __align__(16) __hip_bfloat16 Bs[2][128][32];  // 16 KiB
    int tid = threadIdx.x;
    int lane = tid & 63, w = tid >> 6;
    int bm0 = blockIdx.x * 128, bn0 = blockIdx.y * 128;
    int wm = (w >> 1) * 64, wn = (w & 1) * 64;

    // staging: wave w covers rows [w*32, w*32+32) of each tile, 2 loads each
    int srow = w * 32 + (lane >> 2);
    int scol = (lane & 3) * 8;
    const __hip_bfloat16* ga0 = Ab + (size_t)(bm0 + srow) * 4096 + scol;
    const __hip_bfloat16* ga1 = Ab + (size_t)(bm0 + srow + 16) * 4096 + scol;
    const __hip_bfloat16* gb0 = Bb + (size_t)(bn0 + srow) * 4096 + scol;
    const __hip_bfloat16* gb1 = Bb + (size_t)(bn0 + srow + 16) * 4096 + scol;

    f32x4 acc[4][4] = {};
    int fm = lane & 15;           // fragment row/col lane
    int fk = (lane >> 4) * 8;     // k offset within BK

    // prologue: stage tile 0 into buf 0
    {
        GLOAD_LDS16(ga0, &As[0][w * 32][0]);
        GLOAD_LDS16(ga1, &As[0][w * 32 + 16][0]);
        GLOAD_LDS16(gb0, &Bs[0][w * 32][0]);
        GLOAD_LDS16(gb1, &Bs[0][w * 32 + 16][0]);
    }
    __syncthreads();

    int buf = 0;
    for (int t = 0; t < 128; ++t) {
        if (t + 1 < 128) {
            int k0 = (t + 1) * 32;
            GLOAD_LDS16(ga0 + k0, &As[buf ^ 1][w * 32][0]);
            GLOAD_LDS16(ga1 + k0, &As[buf ^ 1][w * 32 + 16][0]);
            GLOAD_LDS16(gb0 + k0, &Bs[buf ^ 1][w * 32][0]);
            GLOAD_LDS16(gb1 + k0, &Bs[buf ^ 1][w * 32 + 16][0]);
        }
        bf16x8 af[4], bfr[4];
        #pragma unroll
        for (int i = 0; i < 4; ++i)
            af[i] = *(const bf16x8*)&As[buf][wm + i * 16 + fm][fk];
        #pragma unroll
        for (int j = 0; j < 4; ++j)
            bfr[j] = *(const bf16x8*)&Bs[buf][wn + j * 16 + fm][fk];
        #pragma unroll
        for (int i = 0; i < 4; ++i)
            #pragma unroll
            for (int j = 0; j < 4; ++j)
                acc[i][j] = __builtin_amdgcn_mfma_f32_16x16x32_bf16(af[i], bfr[j], acc[i][j], 0, 0, 0);
        __syncthreads();   // drains vmcnt (staged tile ready) + protects buf reuse
        buf ^= 1;
    }

    // epilogue: D col = lane&15, row = (lane>>4)*4 + reg   [HW-verified mapping]
    #pragma unroll
    for (int i = 0; i < 4; ++i) {
        #pragma unroll
        for (int j = 0; j < 4; ++j) {
            int row = bm0 + wm + i * 16 + (lane >> 4) * 4;
            int col = bn0 + wn + j * 16 + (lane & 15);
            #pragma unroll
            for (int r = 0; r < 4; ++r)
                Cm[(size_t)(row + r) * 1024 + col] = acc[i][j][r];
        }
    }
}

// ---------------------------------------------------------------------------
// K5: transposed-conv gather + /4.
// ---------------------------------------------------------------------------
__global__ void scatterD(const float* __restrict__ Mo, float* __restrict__ Dc) {
    int idx = blockIdx.x * 256 + threadIdx.x;
    int ox = idx & 127, oy = (idx >> 7) & 127, c = idx >> 14;
    float acc = 0.f;
    #pragma unroll
    for (int ky = 0; ky < 4; ++ky) {
        int ty = oy + 1 - ky;
        if (ty & 1) continue;
        int iy = ty >> 1;
        if (iy < 0 || iy >= 64) continue;
        #pragma unroll
        for (int kx = 0; kx < 4; ++kx) {
            int txx = ox + 1 - kx;
            if (txx & 1) continue;
            int ix = txx >> 1;
            if (ix < 0 || ix >= 64) continue;
            acc += Mo[(size_t)(iy * 64 + ix) * 1024 + c * 16 + ky * 4 + kx];
        }
    }
    Dc[idx] = acc * 0.25f;
}

// ---------------------------------------------------------------------------
// K6/K7: 3x3 conv (pad 1) + bias + ELU on [64][128][128].
// ---------------------------------------------------------------------------
__global__ void conv3x3_elu(const float* __restrict__ X, const float* __restrict__ W,
                            const float* __restrict__ Bi, float* __restrict__ Y) {
    int co = blockIdx.x;
    int y = blockIdx.y * 2 + (threadIdx.x >> 7);
    int x = threadIdx.x & 127;
    int ky0 = (y == 0) ? 1 : 0, ky1 = (y == 127) ? 2 : 3;
    int kx0 = (x == 0) ? 1 : 0, kx1 = (x == 127) ? 2 : 3;
    float acc = Bi[co];
    const float* wp = W + co * 576;
    for (int ci = 0; ci < 64; ++ci) {
        const float* xp = X + ci * 16384;
        const float* wc = wp + ci * 9;
        for (int ky = ky0; ky < ky1; ++ky) {
            int yy = y + ky - 1;
            for (int kx = kx0; kx < kx1; ++kx) {
                int xx = x + kx - 1;
                acc += xp[yy * 128 + xx] * wc[ky * 3 + kx];
            }
        }
    }
    Y[co * 16384 + y * 128 + x] = acc > 0.f ? acc : expm1f(acc);
}

// ---------------------------------------------------------------------------
extern "C" void kernel_launch(void* const* d_in, const int* in_sizes, int n_in,
                              void* d_out, int out_size, void* d_ws, size_t ws_size,
                              hipStream_t stream) {
    const float* raw_w  = (const float*)d_in[0];
    const float* mm     = (const float*)d_in[1];
    const float* scores = (const float*)d_in[2];
    const float* w1     = (const float*)d_in[3];
    const float* b1     = (const float*)d_in[4];
    const float* w2     = (const float*)d_in[5];
    const float* b2     = (const float*)d_in[6];
    float* out = (float*)d_out;

    char* ws = (char*)d_ws;
    // region [0,64 MiB): A1 during fuse; then Pt/Wt/partials/Mo
    float*          A1 = (float*)ws;
    __hip_bfloat16* Pt = (__hip_bfloat16*)ws;                    // 32 MiB
    __hip_bfloat16* Wt = (__hip_bfloat16*)(ws + (32ull << 20));  // 8 MiB
    float*          Pm = (float*)(ws + (40ull << 20));           // 512 KiB
    float*          Ps = (float*)(ws + (40ull << 20) + (512u << 10));
    float*          Qm = (float*)(ws + (41ull << 20));           // 16 KiB
    float*          Qi = (float*)(ws + (41ull << 20) + (64u << 10));
    float*          Mo = (float*)(ws + (42ull << 20));           // 16 MiB
    // region [64,128 MiB): F during fuse/softmax; then Dc/Y1
    float*          F  = (float*)(ws + (64ull << 20));           // 64 MiB
    float*          Dc = (float*)(ws + (64ull << 20));           // 4 MiB (F dead)
    float*          Y1 = (float*)(ws + (68ull << 20));           // 4 MiB

    fuse1<<<dim3(16, 4096), 256, 0, stream>>>(scores, A1);
    fuse2<<<4096, 256, 0, stream>>>(A1, F);
    transW<<<dim3(16, 64), 256, 0, stream>>>(raw_w, Wt);         // after fuse2 (aliases A1)
    softPart<<<dim3(64, 32), 256, 0, stream>>>(F, mm, Pm, Ps);
    softComb<<<16, 256, 0, stream>>>(Pm, Ps, Qm, Qi);
    normTransP<<<dim3(64, 64), 256, 0, stream>>>(F, mm, Qm, Qi, Pt);
    gemmMfma<<<dim3(32, 8), 256, 0, stream>>>(Pt, Wt, Mo);
    scatterD<<<4096, 256, 0, stream>>>(Mo, Dc);
    conv3x3_elu<<<dim3(64, 64), 256, 0, stream>>>(Dc, w1, b1, Y1);
    conv3x3_elu<<<dim3(64, 64), 256, 0, stream>>>(Y1, w2, b2, out);
}

// Round 4
// 254.119 us; speedup vs baseline: 6.8772x; 2.8185x over previous
//
#include <hip/hip_runtime.h>
#include <hip/hip_bf16.h>
#include <math.h>

// Problem constants
#define NL 4096     // L patches
#define NQ 4096     // HS*WS pixels
#define SCALE 10.0f

typedef __bf16 bf16x8 __attribute__((ext_vector_type(8)));
typedef float  f32x4  __attribute__((ext_vector_type(4)));

#define GLOAD_LDS16(gp, lp)                                                        \
    __builtin_amdgcn_global_load_lds((const __attribute__((address_space(1))) void*)(gp), \
                                     (__attribute__((address_space(3))) void*)(lp), \
                                     16, 0, 0)

// ---------------------------------------------------------------------------
// K1: first diagonal fuse pass on the flattened [4096 x 4096] image.
// ---------------------------------------------------------------------------
__global__ void fuse1(const float* __restrict__ S, float* __restrict__ A1) {
    int c = blockIdx.x * 256 + threadIdx.x;
    int r = blockIdx.y;
    float acc = S[r * 4096 + c];
    if (r > 0 && c > 0)        acc += S[(r - 1) * 4096 + (c - 1)];
    if (r < 4095 && c < 4095)  acc += S[(r + 1) * 4096 + (c + 1)];
    A1[r * 4096 + c] = acc;
}

// ---------------------------------------------------------------------------
// K2: second diagonal fuse pass through the transposed view.
// ---------------------------------------------------------------------------
__global__ void fuse2(const float* __restrict__ A1, float* __restrict__ F) {
    int l = blockIdx.x;
    int hb = l >> 6, wb = l & 63;
    int r2 = wb * 64 + hb;
    for (int q = threadIdx.x; q < NQ; q += 256) {
        int hs = q >> 6, ws = q & 63;
        int c2 = ws * 64 + hs;
        float acc = 0.f;
        #pragma unroll
        for (int d = -1; d <= 1; ++d) {
            int r2d = r2 + d, c2d = c2 + d;
            if (r2d >= 0 && r2d < 4096 && c2d >= 0 && c2d < 4096) {
                int wbp = r2d >> 6, hbp = r2d & 63;
                int wsp = c2d >> 6, hsp = c2d & 63;
                acc += A1[(hbp * 64 + wbp) * 4096 + (hsp * 64 + wsp)];
            }
        }
        F[l * 4096 + q] = acc;
    }
}

// ---------------------------------------------------------------------------
// S1: partial softmax stats. Block (qt,lc): 64 q cols, 128-l chunk.
// ---------------------------------------------------------------------------
__global__ __launch_bounds__(256) void softPart(const float* __restrict__ F,
                                                const float* __restrict__ mm,
                                                float* __restrict__ Pm,
                                                float* __restrict__ Ps) {
    int qt = blockIdx.x, lc = blockIdx.y;
    int qo = threadIdx.x & 63, lg = threadIdx.x >> 6;
    int q = qt * 64 + qo;
    __shared__ float red[4][64];

    float sv[32];
    float m = -1e30f;
    #pragma unroll
    for (int i = 0; i < 32; ++i) {
        int l = lc * 128 + i * 4 + lg;
        float s = F[(size_t)l * 4096 + q] * mm[l] * SCALE;
        sv[i] = s;
        m = fmaxf(m, s);
    }
    red[lg][qo] = m;
    __syncthreads();
    m = fmaxf(fmaxf(red[0][qo], red[1][qo]), fmaxf(red[2][qo], red[3][qo]));
    __syncthreads();

    float sum = 0.f;
    #pragma unroll
    for (int i = 0; i < 32; ++i) sum += __expf(sv[i] - m);
    red[lg][qo] = sum;
    __syncthreads();
    if (lg == 0) {
        sum = red[0][qo] + red[1][qo] + red[2][qo] + red[3][qo];
        Pm[lc * 4096 + q] = m;
        Ps[lc * 4096 + q] = sum;
    }
}

// ---------------------------------------------------------------------------
// S2: combine 32 chunk partials per q.
// ---------------------------------------------------------------------------
__global__ void softComb(const float* __restrict__ Pm, const float* __restrict__ Ps,
                         float* __restrict__ Qm, float* __restrict__ Qi) {
    int q = blockIdx.x * 256 + threadIdx.x;
    float M = -1e30f;
    #pragma unroll
    for (int i = 0; i < 32; ++i) M = fmaxf(M, Pm[i * 4096 + q]);
    float S = 0.f;
    #pragma unroll
    for (int i = 0; i < 32; ++i) S += Ps[i * 4096 + q] * __expf(Pm[i * 4096 + q] - M);
    Qm[q] = M;
    Qi[q] = 1.0f / S;
}

// ---------------------------------------------------------------------------
// S3: normalize + bf16 convert + transpose. Pt[m=q][k=l] = bf16(P[l][q]).
// ---------------------------------------------------------------------------
__global__ __launch_bounds__(256) void normTransP(const float* __restrict__ F,
                                                  const float* __restrict__ mm,
                                                  const float* __restrict__ Qm,
                                                  const float* __restrict__ Qi,
                                                  __hip_bfloat16* __restrict__ Pt) {
    __shared__ float T[64][65];
    int qt = blockIdx.x, lt = blockIdx.y;
    int c = threadIdx.x & 63;
    int q = qt * 64 + c;
    float qm = Qm[q], qi = Qi[q];
    #pragma unroll
    for (int p = 0; p < 16; ++p) {
        int r = p * 4 + (threadIdx.x >> 6);
        int l = lt * 64 + r;
        float mml = mm[l];
        float s = F[(size_t)l * 4096 + q] * mml * SCALE - qm;
        T[r][c] = mml * __expf(s) * qi;
    }
    __syncthreads();
    #pragma unroll
    for (int p = 0; p < 16; ++p) {
        int r = p * 4 + (threadIdx.x >> 6);
        Pt[(size_t)(qt * 64 + r) * 4096 + lt * 64 + c] = (__hip_bfloat16)T[c][r];
    }
}

// ---------------------------------------------------------------------------
// Wt: transpose + convert raw_w [k][n] fp32 -> Wt [n][k] bf16.
// ---------------------------------------------------------------------------
__global__ __launch_bounds__(256) void transW(const float* __restrict__ Wsrc,
                                              __hip_bfloat16* __restrict__ Wt) {
    __shared__ float T[64][65];
    int nt = blockIdx.x, kt = blockIdx.y;
    int c = threadIdx.x & 63;
    #pragma unroll
    for (int p = 0; p < 16; ++p) {
        int r = p * 4 + (threadIdx.x >> 6);
        T[r][c] = Wsrc[(size_t)(kt * 64 + r) * 1024 + nt * 64 + c];
    }
    __syncthreads();
    #pragma unroll
    for (int p = 0; p < 16; ++p) {
        int r = p * 4 + (threadIdx.x >> 6);
        Wt[(size_t)(nt * 64 + r) * 4096 + kt * 64 + c] = (__hip_bfloat16)T[c][r];
    }
}

// ---------------------------------------------------------------------------
// Wc prep: conv weight [co][ci][3][3] fp32 -> Wc[kyx][co][ci] bf16.
// ---------------------------------------------------------------------------
__global__ void transWc(const float* __restrict__ Wsrc, __hip_bfloat16* __restrict__ Wd) {
    int t = blockIdx.x * 256 + threadIdx.x;   // kyx*4096 + co*64 + ci
    int kyx = t >> 12;
    int co = (t >> 6) & 63;
    int ci = t & 63;
    Wd[t] = (__hip_bfloat16)Wsrc[co * 576 + ci * 9 + kyx];
}

// ---------------------------------------------------------------------------
// K4: bf16 MFMA GEMM. Mo[m=4096][n=1024] = sum_k Pt[m][k] * Wt[n][k]^T.
// ---------------------------------------------------------------------------
__global__ __launch_bounds__(256) void gemmMfma(const __hip_bfloat16* __restrict__ Ab,
                                                const __hip_bfloat16* __restrict__ Bb,
                                                float* __restrict__ Cm) {
    __shared__ __align__(16) __hip_bfloat16 As[2][128][32];
    __shared__ __align__(16) __hip_bfloat16 Bs[2][128][32];
    int tid = threadIdx.x;
    int lane = tid & 63, w = tid >> 6;
    int bm0 = blockIdx.x * 128, bn0 = blockIdx.y * 128;
    int wm = (w >> 1) * 64, wn = (w & 1) * 64;

    int srow = w * 32 + (lane >> 2);
    int scol = (lane & 3) * 8;
    const __hip_bfloat16* ga0 = Ab + (size_t)(bm0 + srow) * 4096 + scol;
    const __hip_bfloat16* ga1 = Ab + (size_t)(bm0 + srow + 16) * 4096 + scol;
    const __hip_bfloat16* gb0 = Bb + (size_t)(bn0 + srow) * 4096 + scol;
    const __hip_bfloat16* gb1 = Bb + (size_t)(bn0 + srow + 16) * 4096 + scol;

    f32x4 acc[4][4] = {};
    int fm = lane & 15;
    int fk = (lane >> 4) * 8;

    {
        GLOAD_LDS16(ga0, &As[0][w * 32][0]);
        GLOAD_LDS16(ga1, &As[0][w * 32 + 16][0]);
        GLOAD_LDS16(gb0, &Bs[0][w * 32][0]);
        GLOAD_LDS16(gb1, &Bs[0][w * 32 + 16][0]);
    }
    __syncthreads();

    int buf = 0;
    for (int t = 0; t < 128; ++t) {
        if (t + 1 < 128) {
            int k0 = (t + 1) * 32;
            GLOAD_LDS16(ga0 + k0, &As[buf ^ 1][w * 32][0]);
            GLOAD_LDS16(ga1 + k0, &As[buf ^ 1][w * 32 + 16][0]);
            GLOAD_LDS16(gb0 + k0, &Bs[buf ^ 1][w * 32][0]);
            GLOAD_LDS16(gb1 + k0, &Bs[buf ^ 1][w * 32 + 16][0]);
        }
        bf16x8 af[4], bfr[4];
        #pragma unroll
        for (int i = 0; i < 4; ++i)
            af[i] = *(const bf16x8*)&As[buf][wm + i * 16 + fm][fk];
        #pragma unroll
        for (int j = 0; j < 4; ++j)
            bfr[j] = *(const bf16x8*)&Bs[buf][wn + j * 16 + fm][fk];
        #pragma unroll
        for (int i = 0; i < 4; ++i)
            #pragma unroll
            for (int j = 0; j < 4; ++j)
                acc[i][j] = __builtin_amdgcn_mfma_f32_16x16x32_bf16(af[i], bfr[j], acc[i][j], 0, 0, 0);
        __syncthreads();
        buf ^= 1;
    }

    #pragma unroll
    for (int i = 0; i < 4; ++i) {
        #pragma unroll
        for (int j = 0; j < 4; ++j) {
            int row = bm0 + wm + i * 16 + (lane >> 4) * 4;
            int col = bn0 + wn + j * 16 + (lane & 15);
            #pragma unroll
            for (int r = 0; r < 4; ++r)
                Cm[(size_t)(row + r) * 1024 + col] = acc[i][j][r];
        }
    }
}

// ---------------------------------------------------------------------------
// K5: transposed-conv gather + /4 -> padded NHWC bf16 Xp[130][130][64].
// Border must be pre-zeroed (memset).
// ---------------------------------------------------------------------------
__global__ void scatterD(const float* __restrict__ Mo, __hip_bfloat16* __restrict__ Xp) {
    int c = threadIdx.x & 63;
    int pix = blockIdx.x * 4 + (threadIdx.x >> 6);
    int ox = pix & 127, oy = pix >> 7;
    float acc = 0.f;
    #pragma unroll
    for (int ky = 0; ky < 4; ++ky) {
        int ty = oy + 1 - ky;
        if (ty & 1) continue;
        int iy = ty >> 1;
        if (iy < 0 || iy >= 64) continue;
        #pragma unroll
        for (int kx = 0; kx < 4; ++kx) {
            int txx = ox + 1 - kx;
            if (txx & 1) continue;
            int ix = txx >> 1;
            if (ix < 0 || ix >= 64) continue;
            acc += Mo[(size_t)(iy * 64 + ix) * 1024 + c * 16 + ky * 4 + kx];
        }
    }
    Xp[((size_t)(oy + 1) * 130 + ox + 1) * 64 + c] = (__hip_bfloat16)(acc * 0.25f);
}

// ---------------------------------------------------------------------------
// K6/K7: 3x3 conv + bias + ELU as 9-offset implicit MFMA GEMM.
// Input: padded NHWC bf16 [130][130][64]. Weights: Wc[kyx][co][ci] bf16.
// Block = 64 pixels (one half-row) x 64 co; wave w = 64 pixels x co [w*16,w*16+16).
// B entirely in registers (18 bf16x8), A direct from global. No LDS/barriers.
// MODE 0: ELU -> padded NHWC bf16 Yp.  MODE 1: ELU -> NCHW fp32 Yo.
// ---------------------------------------------------------------------------
template <int MODE>
__global__ __launch_bounds__(256) void convMfma(const __hip_bfloat16* __restrict__ Xp,
                                                const __hip_bfloat16* __restrict__ Wc,
                                                const float* __restrict__ Bi,
                                                __hip_bfloat16* __restrict__ Yp,
                                                float* __restrict__ Yo) {
    int tid = threadIdx.x, lane = tid & 63, w = tid >> 6;
    int y = blockIdx.x >> 1, x0 = (blockIdx.x & 1) * 64;
    int co0 = w * 16;
    int fl = lane & 15, fh = lane >> 4;

    // preload all weights for this wave's 16 co into registers
    bf16x8 wb[3][3][2];
    #pragma unroll
    for (int ky = 0; ky < 3; ++ky)
        #pragma unroll
        for (int kx = 0; kx < 3; ++kx)
            #pragma unroll
            for (int kc = 0; kc < 2; ++kc)
                wb[ky][kx][kc] = *(const bf16x8*)&Wc[(size_t)((ky * 3 + kx) * 64 + co0 + fl) * 64 + kc * 32 + fh * 8];

    f32x4 acc[4] = {};
    #pragma unroll
    for (int ky = 0; ky < 3; ++ky) {
        #pragma unroll
        for (int kx = 0; kx < 3; ++kx) {
            const __hip_bfloat16* xrow = Xp + ((size_t)(y + ky) * 130 + x0 + kx) * 64;
            #pragma unroll
            for (int kc = 0; kc < 2; ++kc) {
                #pragma unroll
                for (int mt = 0; mt < 4; ++mt) {
                    bf16x8 af = *(const bf16x8*)&xrow[(mt * 16 + fl) * 64 + kc * 32 + fh * 8];
                    acc[mt] = __builtin_amdgcn_mfma_f32_16x16x32_bf16(af, wb[ky][kx][kc], acc[mt], 0, 0, 0);
                }
            }
        }
    }

    float bias = Bi[co0 + fl];
    #pragma unroll
    for (int mt = 0; mt < 4; ++mt) {
        int xb = x0 + mt * 16 + fh * 4;      // 4 consecutive pixels xb..xb+3
        if (MODE == 0) {
            #pragma unroll
            for (int r = 0; r < 4; ++r) {
                float v = acc[mt][r] + bias;
                v = v > 0.f ? v : expm1f(v);
                Yp[((size_t)(y + 1) * 130 + xb + r + 1) * 64 + co0 + fl] = (__hip_bfloat16)v;
            }
        } else {
            float4 o;
            float* op = (float*)&o;
            #pragma unroll
            for (int r = 0; r < 4; ++r) {
                float v = acc[mt][r] + bias;
                op[r] = v > 0.f ? v : expm1f(v);
            }
            *(float4*)&Yo[(size_t)(co0 + fl) * 16384 + y * 128 + xb] = o;
        }
    }
}

// ---------------------------------------------------------------------------
extern "C" void kernel_launch(void* const* d_in, const int* in_sizes, int n_in,
                              void* d_out, int out_size, void* d_ws, size_t ws_size,
                              hipStream_t stream) {
    const float* raw_w  = (const float*)d_in[0];
    const float* mm     = (const float*)d_in[1];
    const float* scores = (const float*)d_in[2];
    const float* w1     = (const float*)d_in[3];
    const float* b1     = (const float*)d_in[4];
    const float* w2     = (const float*)d_in[5];
    const float* b2     = (const float*)d_in[6];
    float* out = (float*)d_out;

    char* ws = (char*)d_ws;
    // Workspace map (live ranges verified disjoint):
    //  [0,32)   Pt (after A1 dies)        [32,40)  Wt
    //  [40,41)  Pm+Ps                     [41,41.25) Qm,Qi
    //  [41.25,41.5) Wc1,Wc2  <-- moved out of Y1p's shadow (round-3 bug)
    //  [42,58)  Mo                        [58,60.1) Xp
    //  [61,63.1) Y1p                      [64,128) F (dead after normTransP)
    float*          A1  = (float*)ws;
    __hip_bfloat16* Pt  = (__hip_bfloat16*)ws;                    // 32 MiB
    __hip_bfloat16* Wt  = (__hip_bfloat16*)(ws + (32ull << 20));  // 8 MiB
    float*          Pm  = (float*)(ws + (40ull << 20));
    float*          Ps  = (float*)(ws + (40ull << 20) + (512u << 10));
    float*          Qm  = (float*)(ws + (41ull << 20));
    float*          Qi  = (float*)(ws + (41ull << 20) + (64u << 10));
    __hip_bfloat16* Wc1 = (__hip_bfloat16*)(ws + (41ull << 20) + (256u << 10));  // 72 KiB
    __hip_bfloat16* Wc2 = (__hip_bfloat16*)(ws + (41ull << 20) + (384u << 10));  // 72 KiB
    float*          Mo  = (float*)(ws + (42ull << 20));           // 16 MiB
    __hip_bfloat16* Xp  = (__hip_bfloat16*)(ws + (58ull << 20));  // 2.07 MiB padded NHWC
    __hip_bfloat16* Y1p = (__hip_bfloat16*)(ws + (61ull << 20));  // 2.07 MiB padded NHWC
    float*          F   = (float*)(ws + (64ull << 20));           // 64 MiB

    const size_t XP_BYTES = 130ull * 130 * 64 * sizeof(__hip_bfloat16);

    fuse1<<<dim3(16, 4096), 256, 0, stream>>>(scores, A1);
    fuse2<<<4096, 256, 0, stream>>>(A1, F);
    transW<<<dim3(16, 64), 256, 0, stream>>>(raw_w, Wt);     // after fuse2 (aliases A1)
    transWc<<<144, 256, 0, stream>>>(w1, Wc1);
    transWc<<<144, 256, 0, stream>>>(w2, Wc2);
    softPart<<<dim3(64, 32), 256, 0, stream>>>(F, mm, Pm, Ps);
    softComb<<<16, 256, 0, stream>>>(Pm, Ps, Qm, Qi);
    normTransP<<<dim3(64, 64), 256, 0, stream>>>(F, mm, Qm, Qi, Pt);
    gemmMfma<<<dim3(32, 8), 256, 0, stream>>>(Pt, Wt, Mo);
    hipMemsetAsync(Xp, 0, XP_BYTES, stream);
    hipMemsetAsync(Y1p, 0, XP_BYTES, stream);
    scatterD<<<4096, 256, 0, stream>>>(Mo, Xp);
    convMfma<0><<<256, 256, 0, stream>>>(Xp, Wc1, b1, Y1p, nullptr);
    convMfma<1><<<256, 256, 0, stream>>>(Y1p, Wc2, b2, nullptr, out);
}

// Round 5
// 247.292 us; speedup vs baseline: 7.0671x; 1.0276x over previous
//
#include <hip/hip_runtime.h>
#include <hip/hip_bf16.h>
#include <math.h>

// Problem constants
#define NL 4096     // L patches
#define NQ 4096     // HS*WS pixels
#define SCALE 10.0f

typedef __bf16 bf16x8 __attribute__((ext_vector_type(8)));
typedef float  f32x4  __attribute__((ext_vector_type(4)));

#define GLOAD_LDS16(gp, lp)                                                        \
    __builtin_amdgcn_global_load_lds((const __attribute__((address_space(1))) void*)(gp), \
                                     (__attribute__((address_space(3))) void*)(lp), \
                                     16, 0, 0)

// ---------------------------------------------------------------------------
// K1: fused double-diagonal pass. F[l][q] = sum_{d2,d1} S[...] — composition
// of fuse1 (3-tap diagonal on [l][q]) and fuse2 (3-tap diagonal on the
// (hb<->wb, hs<->ws)-transposed flattened image). Saves A1's 128MB round trip.
// ---------------------------------------------------------------------------
__global__ void fuse12(const float* __restrict__ S, float* __restrict__ F) {
    int l = blockIdx.x;
    int hb = l >> 6, wb = l & 63;
    int r2 = wb * 64 + hb;
    for (int q = threadIdx.x; q < NQ; q += 256) {
        int hs = q >> 6, ws = q & 63;
        int c2 = ws * 64 + hs;
        float acc = 0.f;
        #pragma unroll
        for (int d2 = -1; d2 <= 1; ++d2) {
            int r2d = r2 + d2, c2d = c2 + d2;
            if (r2d < 0 || r2d >= 4096 || c2d < 0 || c2d >= 4096) continue;
            int l1 = (r2d & 63) * 64 + (r2d >> 6);
            int q1 = (c2d & 63) * 64 + (c2d >> 6);
            acc += S[(size_t)l1 * 4096 + q1];
            if (l1 > 0 && q1 > 0)       acc += S[(size_t)(l1 - 1) * 4096 + q1 - 1];
            if (l1 < 4095 && q1 < 4095) acc += S[(size_t)(l1 + 1) * 4096 + q1 + 1];
        }
        F[(size_t)l * 4096 + q] = acc;
    }
}

// ---------------------------------------------------------------------------
// S1: partial softmax stats. Block (qt,lc): 64 q cols, 128-l chunk.
// ---------------------------------------------------------------------------
__global__ __launch_bounds__(256) void softPart(const float* __restrict__ F,
                                                const float* __restrict__ mm,
                                                float* __restrict__ Pm,
                                                float* __restrict__ Ps) {
    int qt = blockIdx.x, lc = blockIdx.y;
    int qo = threadIdx.x & 63, lg = threadIdx.x >> 6;
    int q = qt * 64 + qo;
    __shared__ float red[4][64];

    float sv[32];
    float m = -1e30f;
    #pragma unroll
    for (int i = 0; i < 32; ++i) {
        int l = lc * 128 + i * 4 + lg;
        float s = F[(size_t)l * 4096 + q] * mm[l] * SCALE;
        sv[i] = s;
        m = fmaxf(m, s);
    }
    red[lg][qo] = m;
    __syncthreads();
    m = fmaxf(fmaxf(red[0][qo], red[1][qo]), fmaxf(red[2][qo], red[3][qo]));
    __syncthreads();

    float sum = 0.f;
    #pragma unroll
    for (int i = 0; i < 32; ++i) sum += __expf(sv[i] - m);
    red[lg][qo] = sum;
    __syncthreads();
    if (lg == 0) {
        sum = red[0][qo] + red[1][qo] + red[2][qo] + red[3][qo];
        Pm[lc * 4096 + q] = m;
        Ps[lc * 4096 + q] = sum;
    }
}

// ---------------------------------------------------------------------------
// S2: combine 32 chunk partials per q.
// ---------------------------------------------------------------------------
__global__ void softComb(const float* __restrict__ Pm, const float* __restrict__ Ps,
                         float* __restrict__ Qm, float* __restrict__ Qi) {
    int q = blockIdx.x * 256 + threadIdx.x;
    float M = -1e30f;
    #pragma unroll
    for (int i = 0; i < 32; ++i) M = fmaxf(M, Pm[i * 4096 + q]);
    float S = 0.f;
    #pragma unroll
    for (int i = 0; i < 32; ++i) S += Ps[i * 4096 + q] * __expf(Pm[i * 4096 + q] - M);
    Qm[q] = M;
    Qi[q] = 1.0f / S;
}

// ---------------------------------------------------------------------------
// S3: normalize + bf16 convert + transpose. Pt[m=q][k=l] = bf16(P[l][q]).
// ---------------------------------------------------------------------------
__global__ __launch_bounds__(256) void normTransP(const float* __restrict__ F,
                                                  const float* __restrict__ mm,
                                                  const float* __restrict__ Qm,
                                                  const float* __restrict__ Qi,
                                                  __hip_bfloat16* __restrict__ Pt) {
    __shared__ float T[64][65];
    int qt = blockIdx.x, lt = blockIdx.y;
    int c = threadIdx.x & 63;
    int q = qt * 64 + c;
    float qm = Qm[q], qi = Qi[q];
    #pragma unroll
    for (int p = 0; p < 16; ++p) {
        int r = p * 4 + (threadIdx.x >> 6);
        int l = lt * 64 + r;
        float mml = mm[l];
        float s = F[(size_t)l * 4096 + q] * mml * SCALE - qm;
        T[r][c] = mml * __expf(s) * qi;
    }
    __syncthreads();
    #pragma unroll
    for (int p = 0; p < 16; ++p) {
        int r = p * 4 + (threadIdx.x >> 6);
        Pt[(size_t)(qt * 64 + r) * 4096 + lt * 64 + c] = (__hip_bfloat16)T[c][r];
    }
}

// ---------------------------------------------------------------------------
// Wt: transpose + convert raw_w [k][ck] fp32 -> Wt [n][k] bf16, with the
// GEMM N-dim permuted as n = kyx*64 + c (so scatterD reads Mo coalesced).
// ---------------------------------------------------------------------------
__global__ __launch_bounds__(256) void transW(const float* __restrict__ Wsrc,
                                              __hip_bfloat16* __restrict__ Wt) {
    __shared__ float T[64][65];
    int nt = blockIdx.x, kt = blockIdx.y;
    int c = threadIdx.x & 63;
    #pragma unroll
    for (int p = 0; p < 16; ++p) {
        int r = p * 4 + (threadIdx.x >> 6);
        T[r][c] = Wsrc[(size_t)(kt * 64 + r) * 1024 + nt * 64 + c];
    }
    __syncthreads();
    #pragma unroll
    for (int p = 0; p < 16; ++p) {
        int r = p * 4 + (threadIdx.x >> 6);   // r = ck_local; ck = nt*64 + r
        int n_new = (r & 15) * 64 + nt * 4 + (r >> 4);   // kyx*64 + c_chan
        Wt[(size_t)n_new * 4096 + kt * 64 + c] = (__hip_bfloat16)T[c][r];
    }
}

// ---------------------------------------------------------------------------
// Wc prep: conv weight [co][ci][3][3] fp32 -> Wc[kyx][co][ci] bf16.
// ---------------------------------------------------------------------------
__global__ void transWc(const float* __restrict__ Wsrc, __hip_bfloat16* __restrict__ Wd) {
    int t = blockIdx.x * 256 + threadIdx.x;   // kyx*4096 + co*64 + ci
    int kyx = t >> 12;
    int co = (t >> 6) & 63;
    int ci = t & 63;
    Wd[t] = (__hip_bfloat16)Wsrc[co * 576 + ci * 9 + kyx];
}

// ---------------------------------------------------------------------------
// K4: bf16 MFMA GEMM. Mo[m=4096][n=1024] = sum_k Pt[m][k] * Wt[n][k]^T.
// 128x64 tile -> grid 32x16 = 512 blocks = 2 blocks/CU (round-4 fix: was 1).
// XOR bank-swizzle on 16B chunks: phys_chunk = chunk ^ ((row>>1)&3), applied
// BOTH on the global_load_lds source column and the ds_read offset (rule #21:
// LDS dest stays linear). Gives 8 distinct 16B slots per 8-lane read group.
// ---------------------------------------------------------------------------
__global__ __launch_bounds__(256) void gemmMfma(const __hip_bfloat16* __restrict__ Ab,
                                                const __hip_bfloat16* __restrict__ Bb,
                                                float* __restrict__ Cm) {
    __shared__ __align__(16) __hip_bfloat16 As[2][128][32];  // 16 KiB
    __shared__ __align__(16) __hip_bfloat16 Bs[2][64][32];   //  8 KiB
    int tid = threadIdx.x;
    int lane = tid & 63, w = tid >> 6;
    int bm0 = blockIdx.x * 128, bn0 = blockIdx.y * 64;
    int wm = (w >> 1) * 64, wn = (w & 1) * 32;

    // staging: swizzled source column (inverse of the read swizzle)
    int srowA = w * 32 + (lane >> 2);
    int srowB = w * 16 + (lane >> 2);
    int scol = (((lane & 3) ^ ((lane >> 3) & 3))) * 8;   // elements
    const __hip_bfloat16* ga0 = Ab + (size_t)(bm0 + srowA) * 4096 + scol;
    const __hip_bfloat16* ga1 = Ab + (size_t)(bm0 + srowA + 16) * 4096 + scol;
    const __hip_bfloat16* gb0 = Bb + (size_t)(bn0 + srowB) * 4096 + scol;

    f32x4 acc[4][2] = {};
    int fm = lane & 15;
    int fkz = (((lane >> 4) ^ ((lane >> 1) & 3))) * 8;   // swizzled k-offset (elems)

    GLOAD_LDS16(ga0, &As[0][w * 32][0]);
    GLOAD_LDS16(ga1, &As[0][w * 32 + 16][0]);
    GLOAD_LDS16(gb0, &Bs[0][w * 16][0]);
    __syncthreads();

    int buf = 0;
    for (int t = 0; t < 128; ++t) {
        if (t + 1 < 128) {
            int k0 = (t + 1) * 32;
            GLOAD_LDS16(ga0 + k0, &As[buf ^ 1][w * 32][0]);
            GLOAD_LDS16(ga1 + k0, &As[buf ^ 1][w * 32 + 16][0]);
            GLOAD_LDS16(gb0 + k0, &Bs[buf ^ 1][w * 16][0]);
        }
        bf16x8 af[4], bfr[2];
        #pragma unroll
        for (int i = 0; i < 4; ++i)
            af[i] = *(const bf16x8*)&As[buf][wm + i * 16 + fm][fkz];
        #pragma unroll
        for (int j = 0; j < 2; ++j)
            bfr[j] = *(const bf16x8*)&Bs[buf][wn + j * 16 + fm][fkz];
        #pragma unroll
        for (int i = 0; i < 4; ++i)
            #pragma unroll
            for (int j = 0; j < 2; ++j)
                acc[i][j] = __builtin_amdgcn_mfma_f32_16x16x32_bf16(af[i], bfr[j], acc[i][j], 0, 0, 0);
        __syncthreads();
        buf ^= 1;
    }

    // D mapping: col = lane&15, row = (lane>>4)*4 + reg  [HW-verified]
    #pragma unroll
    for (int i = 0; i < 4; ++i) {
        #pragma unroll
        for (int j = 0; j < 2; ++j) {
            int row = bm0 + wm + i * 16 + (lane >> 4) * 4;
            int col = bn0 + wn + j * 16 + (lane & 15);
            #pragma unroll
            for (int r = 0; r < 4; ++r)
                Cm[(size_t)(row + r) * 1024 + col] = acc[i][j][r];
        }
    }
}

// ---------------------------------------------------------------------------
// K5: transposed-conv gather + /4 -> padded NHWC bf16 Xp[130][130][64].
// Mo N-layout is kyx*64+c -> lanes over c read contiguous 256B segments.
// ---------------------------------------------------------------------------
__global__ void scatterD(const float* __restrict__ Mo, __hip_bfloat16* __restrict__ Xp) {
    int c = threadIdx.x & 63;
    int pix = blockIdx.x * 4 + (threadIdx.x >> 6);
    int ox = pix & 127, oy = pix >> 7;
    float acc = 0.f;
    #pragma unroll
    for (int ky = 0; ky < 4; ++ky) {
        int ty = oy + 1 - ky;
        if (ty & 1) continue;
        int iy = ty >> 1;
        if (iy < 0 || iy >= 64) continue;
        #pragma unroll
        for (int kx = 0; kx < 4; ++kx) {
            int txx = ox + 1 - kx;
            if (txx & 1) continue;
            int ix = txx >> 1;
            if (ix < 0 || ix >= 64) continue;
            acc += Mo[(size_t)(iy * 64 + ix) * 1024 + (ky * 4 + kx) * 64 + c];
        }
    }
    Xp[((size_t)(oy + 1) * 130 + ox + 1) * 64 + c] = (__hip_bfloat16)(acc * 0.25f);
}

// ---------------------------------------------------------------------------
// K6/K7: 3x3 conv + bias + ELU as 9-offset implicit MFMA GEMM (B in regs,
// A direct from global NHWC-padded; no LDS, no barriers).
// ---------------------------------------------------------------------------
template <int MODE>
__global__ __launch_bounds__(256) void convMfma(const __hip_bfloat16* __restrict__ Xp,
                                                const __hip_bfloat16* __restrict__ Wc,
                                                const float* __restrict__ Bi,
                                                __hip_bfloat16* __restrict__ Yp,
                                                float* __restrict__ Yo) {
    int tid = threadIdx.x, lane = tid & 63, w = tid >> 6;
    int y = blockIdx.x >> 1, x0 = (blockIdx.x & 1) * 64;
    int co0 = w * 16;
    int fl = lane & 15, fh = lane >> 4;

    bf16x8 wb[3][3][2];
    #pragma unroll
    for (int ky = 0; ky < 3; ++ky)
        #pragma unroll
        for (int kx = 0; kx < 3; ++kx)
            #pragma unroll
            for (int kc = 0; kc < 2; ++kc)
                wb[ky][kx][kc] = *(const bf16x8*)&Wc[(size_t)((ky * 3 + kx) * 64 + co0 + fl) * 64 + kc * 32 + fh * 8];

    f32x4 acc[4] = {};
    #pragma unroll
    for (int ky = 0; ky < 3; ++ky) {
        #pragma unroll
        for (int kx = 0; kx < 3; ++kx) {
            const __hip_bfloat16* xrow = Xp + ((size_t)(y + ky) * 130 + x0 + kx) * 64;
            #pragma unroll
            for (int kc = 0; kc < 2; ++kc) {
                #pragma unroll
                for (int mt = 0; mt < 4; ++mt) {
                    bf16x8 af = *(const bf16x8*)&xrow[(mt * 16 + fl) * 64 + kc * 32 + fh * 8];
                    acc[mt] = __builtin_amdgcn_mfma_f32_16x16x32_bf16(af, wb[ky][kx][kc], acc[mt], 0, 0, 0);
                }
            }
        }
    }

    float bias = Bi[co0 + fl];
    #pragma unroll
    for (int mt = 0; mt < 4; ++mt) {
        int xb = x0 + mt * 16 + fh * 4;
        if (MODE == 0) {
            #pragma unroll
            for (int r = 0; r < 4; ++r) {
                float v = acc[mt][r] + bias;
                v = v > 0.f ? v : expm1f(v);
                Yp[((size_t)(y + 1) * 130 + xb + r + 1) * 64 + co0 + fl] = (__hip_bfloat16)v;
            }
        } else {
            float4 o;
            float* op = (float*)&o;
            #pragma unroll
            for (int r = 0; r < 4; ++r) {
                float v = acc[mt][r] + bias;
                op[r] = v > 0.f ? v : expm1f(v);
            }
            *(float4*)&Yo[(size_t)(co0 + fl) * 16384 + y * 128 + xb] = o;
        }
    }
}

// ---------------------------------------------------------------------------
extern "C" void kernel_launch(void* const* d_in, const int* in_sizes, int n_in,
                              void* d_out, int out_size, void* d_ws, size_t ws_size,
                              hipStream_t stream) {
    const float* raw_w  = (const float*)d_in[0];
    const float* mm     = (const float*)d_in[1];
    const float* scores = (const float*)d_in[2];
    const float* w1     = (const float*)d_in[3];
    const float* b1     = (const float*)d_in[4];
    const float* w2     = (const float*)d_in[5];
    const float* b2     = (const float*)d_in[6];
    float* out = (float*)d_out;

    char* ws = (char*)d_ws;
    // Workspace map (live ranges verified disjoint):
    //  [0,32)   Pt                       [32,40)  Wt
    //  [40,41)  Pm+Ps                    [41,41.25) Qm,Qi
    //  [41.25,41.5) Wc1,Wc2              [42,58)  Mo
    //  [58,60.1) Xp                      [61,63.1) Y1p
    //  [64,128) F
    __hip_bfloat16* Pt  = (__hip_bfloat16*)ws;                    // 32 MiB
    __hip_bfloat16* Wt  = (__hip_bfloat16*)(ws + (32ull << 20));  // 8 MiB
    float*          Pm  = (float*)(ws + (40ull << 20));
    float*          Ps  = (float*)(ws + (40ull << 20) + (512u << 10));
    float*          Qm  = (float*)(ws + (41ull << 20));
    float*          Qi  = (float*)(ws + (41ull << 20) + (64u << 10));
    __hip_bfloat16* Wc1 = (__hip_bfloat16*)(ws + (41ull << 20) + (256u << 10));  // 72 KiB
    __hip_bfloat16* Wc2 = (__hip_bfloat16*)(ws + (41ull << 20) + (384u << 10));  // 72 KiB
    float*          Mo  = (float*)(ws + (42ull << 20));           // 16 MiB
    __hip_bfloat16* Xp  = (__hip_bfloat16*)(ws + (58ull << 20));  // 2.07 MiB
    __hip_bfloat16* Y1p = (__hip_bfloat16*)(ws + (61ull << 20));  // 2.07 MiB
    float*          F   = (float*)(ws + (64ull << 20));           // 64 MiB

    const size_t XP_BYTES = 130ull * 130 * 64 * sizeof(__hip_bfloat16);

    fuse12<<<4096, 256, 0, stream>>>(scores, F);
    transW<<<dim3(16, 64), 256, 0, stream>>>(raw_w, Wt);
    transWc<<<144, 256, 0, stream>>>(w1, Wc1);
    transWc<<<144, 256, 0, stream>>>(w2, Wc2);
    softPart<<<dim3(64, 32), 256, 0, stream>>>(F, mm, Pm, Ps);
    softComb<<<16, 256, 0, stream>>>(Pm, Ps, Qm, Qi);
    normTransP<<<dim3(64, 64), 256, 0, stream>>>(F, mm, Qm, Qi, Pt);
    gemmMfma<<<dim3(32, 16), 256, 0, stream>>>(Pt, Wt, Mo);
    hipMemsetAsync(Xp, 0, XP_BYTES, stream);
    hipMemsetAsync(Y1p, 0, XP_BYTES, stream);
    scatterD<<<4096, 256, 0, stream>>>(Mo, Xp);
    convMfma<0><<<256, 256, 0, stream>>>(Xp, Wc1, b1, Y1p, nullptr);
    convMfma<1><<<256, 256, 0, stream>>>(Y1p, Wc2, b2, nullptr, out);
}